// Round 2
// baseline (300.671 us; speedup 1.0000x reference)
//
#include <hip/hip_runtime.h>

// B=262144, n_in=128, n_middle=512, n_extra=2
// Collapsed math:
//   acc[0:128] = sum_b w_b * x_b ; wsum = sum_b w_b
//   xbar = [acc/wsum, p] ; h = relu(W_in @ xbar) ; o = W_out @ h
//   out = x + o (broadcast over rows)
//
// ws layout (floats):
//   [0          .. 262143]  p4T : per-block partials, TRANSPOSED [col4][block]
//                            (NBLK=2048 blocks x 32 float4 cols, 1 MiB)
//   [262144     .. 264191]  pw  : per-block wsum partials (2048)
//   [264896     .. 265023]  o (128)

#define NBLK_A 2048
#define OFF_PW   262144
#define OFF_O    264896

typedef float f4raw __attribute__((ext_vector_type(4)));  // nontemporal-compatible

__device__ __forceinline__ float4 f4add(float4 a, float4 b) {
    return make_float4(a.x + b.x, a.y + b.y, a.z + b.z, a.w + b.w);
}

// ---- Stage A: per-block weighted partial sums. Simple 1-load/iter grid-stride
// (m13-copy style), 2048 blocks -> full occupancy; NO atomics. (unchanged)
__global__ __launch_bounds__(256) void wreduce_stageA(
        const float4* __restrict__ x4, const float* __restrict__ w,
        float4* __restrict__ p4T, float* __restrict__ pw, int n4) {
    __shared__ float4 smem[256];
    __shared__ float wsh[8];
    const int tid  = threadIdx.x;
    const int colv = tid & 31;                 // i % 32 == colv (stride % 32 == 0)
    const float is0 = (colv == 0) ? 1.0f : 0.0f;
    const int stride = gridDim.x * blockDim.x;

    float4 a = make_float4(0.f, 0.f, 0.f, 0.f);
    float wl = 0.f;
    for (int i = blockIdx.x * blockDim.x + tid; i < n4; i += stride) {
        const float4 v = x4[i];
        const float wv = w[i >> 5];
        a.x += wv * v.x; a.y += wv * v.y; a.z += wv * v.z; a.w += wv * v.w;
        wl += is0 * wv;
    }
    smem[tid] = a;
    if (colv == 0) wsh[tid >> 5] = wl;
    __syncthreads();
    if (tid < 128) smem[tid] = f4add(smem[tid], smem[tid + 128]);
    __syncthreads();
    if (tid < 64)  smem[tid] = f4add(smem[tid], smem[tid + 64]);
    __syncthreads();
    if (tid < 32) {
        float4 r = f4add(smem[tid], smem[tid + 32]);
        p4T[tid * NBLK_A + blockIdx.x] = r;    // transposed for coalesced tail read
    }
    if (tid == 0) {
        float s = 0.f;
        #pragma unroll
        for (int k = 0; k < 8; k++) s += wsh[k];
        pw[blockIdx.x] = s;
    }
}

// ---- Fused tail: ONE block (1024 threads) does stageB reduce + h + o.
// Replaces three dispatches (stageB, h_kernel, o_kernel): removes two
// graph-node boundaries; total traffic ~1.5 MB from L2/L3 on one CU.
__global__ __launch_bounds__(1024) void tail_kernel(
        const float4* __restrict__ p4T, const float* __restrict__ pw,
        const float* __restrict__ p, const float* __restrict__ W_in,
        const float* __restrict__ W_out, float* __restrict__ o_out) {
    __shared__ __align__(16) float xb[128];   // acc (raw weighted sums)
    __shared__ float hs[512];                 // h = relu(...)
    __shared__ float wred[16];                // per-wave wsum partials
    const int t = threadIdx.x;
    const int lane = t & 63, wid = t >> 6;    // 16 waves

    // -- wsum: 2048 partials, all 1024 threads
    {
        float s = pw[t] + pw[t + 1024];
        #pragma unroll
        for (int off = 32; off; off >>= 1) s += __shfl_xor(s, off);
        if (lane == 0) wred[wid] = s;
    }

    // -- acc: 32 float4 columns x 2048 entries; 32 threads per column,
    //    coalesced 512B per half-wave per iteration.
    {
        const int c = t >> 5, j = t & 31;
        const float4* __restrict__ col = p4T + c * NBLK_A;
        float4 a = make_float4(0.f, 0.f, 0.f, 0.f);
        #pragma unroll 8
        for (int k = 0; k < NBLK_A / 32; k++) a = f4add(a, col[j + 32 * k]);
        // reduce across the 32-lane half-wave group (xor offsets stay inside it)
        #pragma unroll
        for (int off = 16; off; off >>= 1) {
            a.x += __shfl_xor(a.x, off);
            a.y += __shfl_xor(a.y, off);
            a.z += __shfl_xor(a.z, off);
            a.w += __shfl_xor(a.w, off);
        }
        if (j == 0) ((float4*)xb)[c] = a;
    }
    __syncthreads();

    float wsum = 0.f;
    #pragma unroll
    for (int k = 0; k < 16; k++) wsum += wred[k];
    const float inv = 1.0f / wsum;

    // -- h: 512 rows, 2 threads per row; thread covers float2 idx q = half,
    //    half+2, ... over the 65 float2 of a 130-float row (last = p-part).
    {
        const int r = t >> 1, half = t & 1;
        const float2* __restrict__ row2 = (const float2*)(W_in + r * 130);
        const float2* __restrict__ acc2 = (const float2*)xb;
        float s = 0.f;
        #pragma unroll
        for (int q = half; q < 64; q += 2) {
            const float2 wv = row2[q];
            const float2 av = acc2[q];
            s += wv.x * av.x + wv.y * av.y;
        }
        s += __shfl_xor(s, 1);                // pair (2r, 2r+1) shares the dot
        if (half == 0) {
            const float2 wp = row2[64];
            const float sp = wp.x * p[0] + wp.y * p[1];
            hs[r] = fmaxf(inv * s + sp, 0.f);
        }
    }
    __syncthreads();

    // -- o: 128 rows, 8 threads per row; thread covers 16 float4 of the
    //    512-wide dot. 8-lane groups are wave-aligned (r = t>>3).
    {
        const int r = t >> 3, sub = t & 7;
        const float4* __restrict__ row4 = (const float4*)(W_out + r * 512);
        const float4* __restrict__ h4 = (const float4*)hs;
        float s = 0.f;
        #pragma unroll
        for (int qq = 0; qq < 16; qq++) {
            const int q = sub * 16 + qq;
            const float4 wv = row4[q];
            const float4 hv = h4[q];
            s += wv.x * hv.x + wv.y * hv.y + wv.z * hv.z + wv.w * hv.w;
        }
        #pragma unroll
        for (int off = 4; off; off >>= 1) s += __shfl_xor(s, off);
        if (sub == 0) o_out[r] = s;
    }
}

// ---- out = x + o : minimal copy-style kernel, nontemporal stores. (unchanged)
__global__ __launch_bounds__(256) void bcast_add_kernel(
        const float4* __restrict__ x4, const float4* __restrict__ o4,
        f4raw* __restrict__ out4, int n4) {
    int i = blockIdx.x * blockDim.x + threadIdx.x;
    const float4 ov = o4[i & 31];              // column invariant: stride % 32 == 0
    const int stride = gridDim.x * blockDim.x;
    for (; i < n4; i += stride) {
        const float4 v = x4[i];
        f4raw r = {v.x + ov.x, v.y + ov.y, v.z + ov.z, v.w + ov.w};
        __builtin_nontemporal_store(r, &out4[i]);
    }
}

extern "C" void kernel_launch(void* const* d_in, const int* in_sizes, int n_in,
                              void* d_out, int out_size, void* d_ws, size_t ws_size,
                              hipStream_t stream) {
    const float* x     = (const float*)d_in[0];
    const float* w     = (const float*)d_in[1];
    const float* p     = (const float*)d_in[2];
    const float* W_in  = (const float*)d_in[3];
    const float* W_out = (const float*)d_in[4];
    float* out = (float*)d_out;
    float* ws  = (float*)d_ws;

    float4* p4T  = (float4*)ws;
    float*  pw   = ws + OFF_PW;
    float*  o    = ws + OFF_O;

    const int n4 = in_sizes[0] / 4;            // 8,388,608 float4s of x

    wreduce_stageA<<<NBLK_A, 256, 0, stream>>>((const float4*)x, w, p4T, pw, n4);
    tail_kernel<<<1, 1024, 0, stream>>>(p4T, pw, p, W_in, W_out, o);
    bcast_add_kernel<<<8192, 256, 0, stream>>>((const float4*)x, (const float4*)o,
                                               (f4raw*)out, n4);
}

// Round 4
// 279.893 us; speedup vs baseline: 1.0742x; 1.0742x over previous
//
#include <hip/hip_runtime.h>

// B=262144, n_in=128, n_middle=512, n_extra=2
// Collapsed math:
//   acc[0:128] = sum_b w_b * x_b ; wsum = sum_b w_b
//   xbar = [acc/wsum, p] ; h = relu(W_in @ xbar) ; o = W_out @ h
//   out = x + o (broadcast over rows)
//
// Structure: 3 dispatches (graph-capture-safe; NO cooperative launch --
// hipLaunchCooperativeKernel invalidates hip-graph capture, round-3 lesson):
//   D1 wreduce_stageA   2048 blocks (unchanged math; also zero-inits barrier ctr)
//   D2 tail_fused       33 blocks, co-resident by construction (33 <= 256 CUs,
//                       GPU idle at dispatch). Internal spin barriers via
//                       device-scope atomics. acc/wsum -> h -> o, every phase
//                       spread over >=32 CUs (round-2 lesson: 1-CU funnel = 45 GB/s).
//   D3 bcast_add        8192 blocks. EXPERIMENT: normal stores (not NT) so the
//                       134 MB out-burst can be absorbed by L3 (fills show
//                       FETCH~0 => full-line streaming writes don't RFO).
//
// ws layout (floats):
//   [0          .. 262143]  p4T : per-block partials, TRANSPOSED [col4][block]
//   [262144     .. 264191]  pw  : per-block wsum partials (2048)
//   [264192     .. 264319]  acc (128)
//   [264320]                wsum
//   [264384     .. 264895]  h (512)
//   [264896     .. 265023]  o (128)
//   [265024]                cnt : spin-barrier counter (int), init'd by stageA

#define NBLK_A 2048
#define OFF_PW   262144
#define OFF_ACC  264192
#define OFF_WSUM 264320
#define OFF_H    264384
#define OFF_O    264896
#define OFF_CNT  265024

typedef float f4raw __attribute__((ext_vector_type(4)));  // nontemporal-compatible

__device__ __forceinline__ float4 f4add(float4 a, float4 b) {
    return make_float4(a.x + b.x, a.y + b.y, a.z + b.z, a.w + b.w);
}

// All-33-block arrive-and-wait. Prior global writes are made device-visible
// (threadfence) before arrival; acquire-load on the counter orders the reads
// after. Safe: all 33 blocks are resident (33 <= #CUs, GPU idle at launch).
__device__ __forceinline__ void grid33_barrier(int* cnt, int target) {
    __syncthreads();
    if (threadIdx.x == 0) {
        __threadfence();
        __hip_atomic_fetch_add(cnt, 1, __ATOMIC_ACQ_REL, __HIP_MEMORY_SCOPE_AGENT);
        while (__hip_atomic_load(cnt, __ATOMIC_ACQUIRE, __HIP_MEMORY_SCOPE_AGENT) < target) {
            __builtin_amdgcn_s_sleep(1);
        }
    }
    __syncthreads();
}

// ---- Stage A: per-block weighted partial sums. 2048 blocks, full occupancy,
// no atomics. (unchanged from the 259 µs version, + barrier-counter init)
__global__ __launch_bounds__(256) void wreduce_stageA(
        const float4* __restrict__ x4, const float* __restrict__ w,
        float4* __restrict__ p4T, float* __restrict__ pw, int* __restrict__ cnt,
        int n4) {
    __shared__ float4 smem[256];
    __shared__ float wsh[8];
    const int tid  = threadIdx.x;
    const int colv = tid & 31;                 // i % 32 == colv (stride % 32 == 0)
    const float is0 = (colv == 0) ? 1.0f : 0.0f;
    const int stride = gridDim.x * blockDim.x;

    float4 a = make_float4(0.f, 0.f, 0.f, 0.f);
    float wl = 0.f;
    for (int i = blockIdx.x * blockDim.x + tid; i < n4; i += stride) {
        const float4 v = x4[i];
        const float wv = w[i >> 5];
        a.x += wv * v.x; a.y += wv * v.y; a.z += wv * v.z; a.w += wv * v.w;
        wl += is0 * wv;
    }
    smem[tid] = a;
    if (colv == 0) wsh[tid >> 5] = wl;
    __syncthreads();
    if (tid < 128) smem[tid] = f4add(smem[tid], smem[tid + 128]);
    __syncthreads();
    if (tid < 64)  smem[tid] = f4add(smem[tid], smem[tid + 64]);
    __syncthreads();
    if (tid < 32) {
        float4 r = f4add(smem[tid], smem[tid + 32]);
        p4T[tid * NBLK_A + blockIdx.x] = r;    // transposed for coalesced tail read
    }
    if (tid == 0) {
        float s = 0.f;
        #pragma unroll
        for (int k = 0; k < 8; k++) s += wsh[k];
        pw[blockIdx.x] = s;
        if (blockIdx.x == 0) *cnt = 0;         // init for tail_fused (stream order)
    }
}

// ---- Fused tail: 33 blocks. Phase A: acc/wsum reduce. Phase B: h. Phase C: o.
// Replaces three dispatches; every phase spans >=32 CUs.
__global__ __launch_bounds__(256) void tail_fused(
        const float4* __restrict__ p4T, const float* __restrict__ pw,
        const float* __restrict__ p, const float* __restrict__ W_in,
        const float* __restrict__ W_out,
        float* __restrict__ acc, float* __restrict__ wsum,
        float* __restrict__ h, float* __restrict__ o, int* __restrict__ cnt) {
    __shared__ float4 smem[256];
    const int t = threadIdx.x, b = blockIdx.x;
    const int lane = t & 63, wid = t >> 6;

    // -- phase A: acc (blocks 0..31: one float4 column of 2048 partials each,
    //    coalesced), wsum (block 32).
    if (b < 32) {
        const float4* __restrict__ col = p4T + b * NBLK_A;
        float4 a = make_float4(0.f, 0.f, 0.f, 0.f);
        #pragma unroll
        for (int k = 0; k < NBLK_A / 256; k++) a = f4add(a, col[t + k * 256]);
        smem[t] = a;
        __syncthreads();
        for (int off = 128; off > 0; off >>= 1) {
            if (t < off) smem[t] = f4add(smem[t], smem[t + off]);
            __syncthreads();
        }
        if (t == 0) ((float4*)acc)[b] = smem[0];
    } else {
        float s = 0.f;
        #pragma unroll
        for (int k = 0; k < NBLK_A / 256; k++) s += pw[t + k * 256];
        ((float*)smem)[t] = s;
        __syncthreads();
        for (int off = 128; off > 0; off >>= 1) {
            if (t < off) ((float*)smem)[t] += ((float*)smem)[t + off];
            __syncthreads();
        }
        if (t == 0) *wsum = ((float*)smem)[0];
    }
    grid33_barrier(cnt, 33);

    // -- phase B: h = relu(W_in @ [acc/wsum, p]). Blocks 0..31, 4 waves each,
    //    one wave per row, 4 passes -> 16 rows per block.
    if (b < 32) {
        const float inv = 1.0f / *wsum;
        const float2 av = ((const float2*)acc)[lane];
        #pragma unroll
        for (int pass = 0; pass < 4; pass++) {
            const int r = b * 16 + wid * 4 + pass;
            const float2* __restrict__ row2 = (const float2*)(W_in + r * 130);
            const float2 wv = row2[lane];
            float s = wv.x * av.x + wv.y * av.y;
            #pragma unroll
            for (int off = 32; off; off >>= 1) s += __shfl_xor(s, off);
            if (lane == 0) {
                const float2 wp = row2[64];
                h[r] = fmaxf(inv * s + wp.x * p[0] + wp.y * p[1], 0.f);
            }
        }
    }
    grid33_barrier(cnt, 66);

    // -- phase C: o = W_out @ h. Blocks 0..31 x 4 waves = 128 waves, 1 row each;
    //    lane l covers float4 chunks l and l+64 of the 512-wide dot.
    if (b < 32) {
        const int r = b * 4 + wid;
        const float4* __restrict__ row4 = (const float4*)(W_out + r * 512);
        const float4* __restrict__ h4 = (const float4*)h;
        const float4 wa = row4[lane],      wb = row4[lane + 64];
        const float4 ha = h4[lane],        hb = h4[lane + 64];
        float s = wa.x*ha.x + wa.y*ha.y + wa.z*ha.z + wa.w*ha.w
                + wb.x*hb.x + wb.y*hb.y + wb.z*hb.z + wb.w*hb.w;
        #pragma unroll
        for (int off = 32; off; off >>= 1) s += __shfl_xor(s, off);
        if (lane == 0) o[r] = s;
    }
}

// ---- out = x + o. NT load of x (dead after this), NORMAL store of out
// (store-mode experiment: 134 MB < 256 MB L3; full-line streaming writes
// don't RFO per the fill kernels' FETCH~0).
__global__ __launch_bounds__(256) void bcast_add_kernel(
        const f4raw* __restrict__ x4, const float4* __restrict__ o4,
        f4raw* __restrict__ out4, int n4) {
    int i = blockIdx.x * blockDim.x + threadIdx.x;
    const float4 ov = o4[i & 31];              // column invariant: stride % 32 == 0
    const int stride = gridDim.x * blockDim.x;
    for (; i < n4; i += stride) {
        const f4raw v = __builtin_nontemporal_load(&x4[i]);
        f4raw r = {v.x + ov.x, v.y + ov.y, v.z + ov.z, v.w + ov.w};
        out4[i] = r;
    }
}

extern "C" void kernel_launch(void* const* d_in, const int* in_sizes, int n_in,
                              void* d_out, int out_size, void* d_ws, size_t ws_size,
                              hipStream_t stream) {
    const float* x     = (const float*)d_in[0];
    const float* w     = (const float*)d_in[1];
    const float* p     = (const float*)d_in[2];
    const float* W_in  = (const float*)d_in[3];
    const float* W_out = (const float*)d_in[4];
    float* out = (float*)d_out;
    float* ws  = (float*)d_ws;

    float4* p4T  = (float4*)ws;
    float*  pw   = ws + OFF_PW;
    float*  acc  = ws + OFF_ACC;
    float*  wsum = ws + OFF_WSUM;
    float*  h    = ws + OFF_H;
    float*  o    = ws + OFF_O;
    int*    cnt  = (int*)(ws + OFF_CNT);

    const int n4 = in_sizes[0] / 4;            // 8,388,608 float4s of x

    wreduce_stageA<<<NBLK_A, 256, 0, stream>>>((const float4*)x, w, p4T, pw, cnt, n4);
    tail_fused<<<33, 256, 0, stream>>>(p4T, pw, p, W_in, W_out, acc, wsum, h, o, cnt);
    bcast_add_kernel<<<8192, 256, 0, stream>>>((const f4raw*)x, (const float4*)o,
                                               (f4raw*)out, n4);
}

// Round 5
// 257.900 us; speedup vs baseline: 1.1658x; 1.0853x over previous
//
#include <hip/hip_runtime.h>

// B=262144, n_in=128, n_middle=512, n_extra=2
// Collapsed math:
//   acc[0:128] = sum_b w_b * x_b ; wsum = sum_b w_b
//   xbar = [acc/wsum, p] ; h = relu(W_in @ xbar) ; o = W_out @ h
//   out = x + o (broadcast over rows)
//
// ROUND-5: exact revert to the round-0 structure (measured 259.1 us, the
// session best). Experiments ruled out by measurement:
//   r2: single-block fused tail      -> +35 us (per-CU BW is ~25-40 GB/s;
//       never funnel MBs through one CU)
//   r3: hipLaunchCooperativeKernel   -> invalidates hip-graph capture
//   r4: 33-block spin-barrier tail + normal stores -> +15 us normalized
//       (agent-scope fence/acquire = L2 writeback/invalidate per poll;
//        L3 does not absorb 134 MB write bursts -- fills prove WRITE drains
//        to HBM at ~6.7 TB/s with FETCH~0 either way)
// Remaining structure: 5 dispatches, every phase spread over >=16 CUs,
// streaming kernels at ~85% HBM ceiling (same % as the harness fills).
//
// ws layout (floats):
//   [0          .. 262143]  p4T : per-block partials, TRANSPOSED [col4][block]
//                            (NBLK=2048 blocks x 32 float4 cols, 1 MiB)
//   [262144     .. 264191]  pw  : per-block wsum partials (2048)
//   [264192     .. 264319]  acc : reduced weighted sum (128)
//   [264320]                wsum
//   [264384     .. 264895]  h (512)
//   [264896     .. 265023]  o (128)

#define NBLK_A 2048
#define OFF_PW   262144
#define OFF_ACC  264192
#define OFF_WSUM 264320
#define OFF_H    264384
#define OFF_O    264896

typedef float f4raw __attribute__((ext_vector_type(4)));  // nontemporal-compatible

__device__ __forceinline__ float4 f4add(float4 a, float4 b) {
    return make_float4(a.x + b.x, a.y + b.y, a.z + b.z, a.w + b.w);
}

// ---- Stage A: per-block weighted partial sums. Simple 1-load/iter grid-stride
// (m13-copy style), 2048 blocks -> full occupancy; NO atomics.
__global__ __launch_bounds__(256) void wreduce_stageA(
        const float4* __restrict__ x4, const float* __restrict__ w,
        float4* __restrict__ p4T, float* __restrict__ pw, int n4) {
    __shared__ float4 smem[256];
    __shared__ float wsh[8];
    const int tid  = threadIdx.x;
    const int colv = tid & 31;                 // i % 32 == colv (stride % 32 == 0)
    const float is0 = (colv == 0) ? 1.0f : 0.0f;
    const int stride = gridDim.x * blockDim.x;

    float4 a = make_float4(0.f, 0.f, 0.f, 0.f);
    float wl = 0.f;
    for (int i = blockIdx.x * blockDim.x + tid; i < n4; i += stride) {
        const float4 v = x4[i];
        const float wv = w[i >> 5];
        a.x += wv * v.x; a.y += wv * v.y; a.z += wv * v.z; a.w += wv * v.w;
        wl += is0 * wv;
    }
    smem[tid] = a;
    if (colv == 0) wsh[tid >> 5] = wl;
    __syncthreads();
    if (tid < 128) smem[tid] = f4add(smem[tid], smem[tid + 128]);
    __syncthreads();
    if (tid < 64)  smem[tid] = f4add(smem[tid], smem[tid + 64]);
    __syncthreads();
    if (tid < 32) {
        float4 r = f4add(smem[tid], smem[tid + 32]);
        p4T[tid * NBLK_A + blockIdx.x] = r;    // transposed for coalesced stage B
    }
    if (tid == 0) {
        float s = 0.f;
        #pragma unroll
        for (int k = 0; k < 8; k++) s += wsh[k];
        pw[blockIdx.x] = s;
    }
}

// ---- Stage B: 33 blocks. Blocks 0..31 reduce one float4 column over 2048
// partials (coalesced); block 32 reduces the 2048 wsum partials.
__global__ __launch_bounds__(256) void wreduce_stageB(
        const float4* __restrict__ p4T, const float* __restrict__ pw,
        float4* __restrict__ acc4, float* __restrict__ wsum) {
    __shared__ float4 smem[256];
    const int t = threadIdx.x, b = blockIdx.x;
    if (b < 32) {
        const float4* __restrict__ col = p4T + b * NBLK_A;
        float4 a = make_float4(0.f, 0.f, 0.f, 0.f);
        #pragma unroll
        for (int k = 0; k < NBLK_A / 256; k++) a = f4add(a, col[t + k * 256]);
        smem[t] = a;
        __syncthreads();
        for (int off = 128; off > 0; off >>= 1) {
            if (t < off) smem[t] = f4add(smem[t], smem[t + off]);
            __syncthreads();
        }
        if (t == 0) acc4[b] = smem[0];
    } else {
        float s = 0.f;
        #pragma unroll
        for (int k = 0; k < NBLK_A / 256; k++) s += pw[t + k * 256];
        ((float*)smem)[t] = s;
        __syncthreads();
        for (int off = 128; off > 0; off >>= 1) {
            if (t < off) ((float*)smem)[t] += ((float*)smem)[t + off];
            __syncthreads();
        }
        if (t == 0) *wsum = ((float*)smem)[0];
    }
}

// ---- h = relu(W_in @ [acc/wsum, p]) : one wave per row (512 rows).
// Lane l covers k = 2l,2l+1 via float2; lane 0 adds the p-part (k=128,129).
__global__ __launch_bounds__(512) void h_kernel(
        const float* __restrict__ acc, const float* __restrict__ wsum_p,
        const float* __restrict__ p, const float* __restrict__ W_in,
        float* __restrict__ h) {
    const int lane = threadIdx.x & 63;
    const int r = blockIdx.x * 8 + (threadIdx.x >> 6);
    const float inv = 1.0f / *wsum_p;
    const float2* __restrict__ row2 = (const float2*)(W_in + r * 130);
    const float2 wv = row2[lane];
    const float2 av = ((const float2*)acc)[lane];
    float s = wv.x * av.x + wv.y * av.y;
    #pragma unroll
    for (int off = 32; off; off >>= 1) s += __shfl_xor(s, off);
    if (lane == 0) {
        const float2 wp = row2[64];
        const float sp = wp.x * p[0] + wp.y * p[1];
        h[r] = fmaxf(inv * s + sp, 0.f);
    }
}

// ---- o = W_out @ h : one wave per row (128 rows); lane l covers float4
// chunks l and l+64 of the 512-wide dot.
__global__ __launch_bounds__(512) void o_kernel(
        const float* __restrict__ h, const float* __restrict__ W_out,
        float* __restrict__ o) {
    const int lane = threadIdx.x & 63;
    const int r = blockIdx.x * 8 + (threadIdx.x >> 6);
    const float4* __restrict__ row4 = (const float4*)(W_out + r * 512);
    const float4* __restrict__ h4 = (const float4*)h;
    const float4 wa = row4[lane],      wb = row4[lane + 64];
    const float4 ha = h4[lane],        hb = h4[lane + 64];
    float s = wa.x*ha.x + wa.y*ha.y + wa.z*ha.z + wa.w*ha.w
            + wb.x*hb.x + wb.y*hb.y + wb.z*hb.z + wb.w*hb.w;
    #pragma unroll
    for (int off = 32; off; off >>= 1) s += __shfl_xor(s, off);
    if (lane == 0) o[r] = s;
}

// ---- out = x + o : minimal copy-style kernel, nontemporal stores.
__global__ __launch_bounds__(256) void bcast_add_kernel(
        const float4* __restrict__ x4, const float4* __restrict__ o4,
        f4raw* __restrict__ out4, int n4) {
    int i = blockIdx.x * blockDim.x + threadIdx.x;
    const float4 ov = o4[i & 31];              // column invariant: stride % 32 == 0
    const int stride = gridDim.x * blockDim.x;
    for (; i < n4; i += stride) {
        const float4 v = x4[i];
        f4raw r = {v.x + ov.x, v.y + ov.y, v.z + ov.z, v.w + ov.w};
        __builtin_nontemporal_store(r, &out4[i]);
    }
}

extern "C" void kernel_launch(void* const* d_in, const int* in_sizes, int n_in,
                              void* d_out, int out_size, void* d_ws, size_t ws_size,
                              hipStream_t stream) {
    const float* x     = (const float*)d_in[0];
    const float* w     = (const float*)d_in[1];
    const float* p     = (const float*)d_in[2];
    const float* W_in  = (const float*)d_in[3];
    const float* W_out = (const float*)d_in[4];
    float* out = (float*)d_out;
    float* ws  = (float*)d_ws;

    float4* p4T  = (float4*)ws;
    float*  pw   = ws + OFF_PW;
    float*  acc  = ws + OFF_ACC;
    float*  wsum = ws + OFF_WSUM;
    float*  h    = ws + OFF_H;
    float*  o    = ws + OFF_O;

    const int n4 = in_sizes[0] / 4;            // 8,388,608 float4s of x

    wreduce_stageA<<<NBLK_A, 256, 0, stream>>>((const float4*)x, w, p4T, pw, n4);
    wreduce_stageB<<<33, 256, 0, stream>>>(p4T, pw, (float4*)acc, wsum);
    h_kernel<<<64, 512, 0, stream>>>(acc, wsum, p, W_in, h);
    o_kernel<<<16, 512, 0, stream>>>(h, W_out, o);
    bcast_add_kernel<<<8192, 256, 0, stream>>>((const float4*)x, (const float4*)o,
                                               (f4raw*)out, n4);
}